// Round 3
// baseline (97.148 us; speedup 1.0000x reference)
//
#include <hip/hip_runtime.h>
#include <math.h>

// Problem constants (fixed by the reference)
#define BD   128      // batch == hidden
#define NCOL 1024     // img dim == txt dim
#define NE   32768    // edges
#define CAP  128      // bucket capacity (Poisson lambda=32, max ~60; 128 safe)

// ---------------------------------------------------------------------------
// K1 "prep": three independent task groups co-scheduled in one launch:
//  blocks 0..255  : H precompute
//    HimgT[i,h] = sum_b img[b,i]*W1[h,b] (+ b1[h]);  HtxtT likewise (txt half)
//  blocks 256..511: 32x32 tiled transposes img->imgT, text->textT
//  blocks 512..575: bucket fill via per-block LDS counters (NO global memset,
//    NO global atomics): block owns 32 columns of one side, scans the edge
//    array (int4, L2-hot), LDS-atomicAdd on match, writes cnt[] plain.
// ---------------------------------------------------------------------------
__global__ __launch_bounds__(256) void prep_kernel(
    const float* __restrict__ img, const float* __restrict__ text,
    const int* __restrict__ src, const int* __restrict__ tgt,
    const float* __restrict__ W1, const float* __restrict__ b1,
    float* __restrict__ HimgT, float* __restrict__ HtxtT,
    float* __restrict__ imgT, float* __restrict__ textT,
    int* __restrict__ cnt,
    int* __restrict__ list_src, int* __restrict__ list_tgt)
{
    __shared__ __align__(16) float Wl[64 * 129];  // 33 KB (h) / reused elsewhere
    __shared__ __align__(16) float Sl[128 * 8];   // 4 KB (h) / fill counters
    const int blk = blockIdx.x, tid = threadIdx.x;

    if (blk < 256) {
        // ---- H precompute ----
        const int side = blk >> 7;            // 0: img, 1: txt
        const int i0 = (blk & 127) * 8;
        const float* S = side ? text : img;
        float* Dst = side ? HtxtT : HimgT;
        const int soff = side * 128;

        {   // stage S tile: 128 rows x 8 floats = 256 float4 (coalesced)
            int b = tid >> 1, q = tid & 1;
            ((float4*)Sl)[tid] = *(const float4*)(S + b * 1024 + i0 + q * 4);
        }
        const int h = tid & 127, iq = tid >> 7;
        float acc[4] = {0.f, 0.f, 0.f, 0.f};
        #pragma unroll
        for (int half = 0; half < 2; half++) {
            __syncthreads();
            for (int idx = tid; idx < 8192; idx += 256) {
                int hh = idx >> 6, bb = idx & 63;
                Wl[bb * 129 + hh] = W1[hh * 256 + soff + half * 64 + bb];
            }
            __syncthreads();
            #pragma unroll 8
            for (int bb = 0; bb < 64; bb++) {
                int b = half * 64 + bb;
                float w = Wl[bb * 129 + h];                        // conflict-free
                float4 s4 = *(const float4*)(Sl + b * 8 + iq * 4); // broadcast
                acc[0] += s4.x * w; acc[1] += s4.y * w;
                acc[2] += s4.z * w; acc[3] += s4.w * w;
            }
        }
        float bias = side ? 0.f : b1[h];
        #pragma unroll
        for (int r = 0; r < 4; r++)
            Dst[(i0 + iq * 4 + r) * 128 + h] = acc[r] + bias;
    } else if (blk < 512) {
        // ---- 32x32 tiled transpose (conflict-free via +1 pad) ----
        float (*lds)[33] = (float(*)[33])Wl;     // 32*33 floats of Wl
        const int t = blk - 256;                 // 0..255
        const float* S = (t < 128) ? img : text;
        float* D = (t < 128) ? imgT : textT;
        const int tile = t & 127;                // 4 row-tiles x 32 col-tiles
        const int rt = tile >> 5, ct = tile & 31;
        const int x = tid & 31, y = tid >> 5;    // y 0..7
        #pragma unroll
        for (int k = 0; k < 4; k++) {
            int r = y + k * 8;
            lds[r][x] = S[(rt * 32 + r) * 1024 + ct * 32 + x];
        }
        __syncthreads();
        #pragma unroll
        for (int k = 0; k < 4; k++) {
            int r = y + k * 8;
            D[(ct * 32 + r) * 128 + rt * 32 + x] = lds[x][r];
        }
    } else {
        // ---- bucket fill: 64 blocks, each owns 32 columns of one side ----
        int* lc = (int*)Sl;                      // 32 LDS counters
        const int fb = blk - 512;                // 0..63
        const int side = fb >> 5;                // 0: src buckets, 1: tgt
        const int base = (fb & 31) * 32;         // column range [base, base+32)
        const int* E = side ? tgt : src;
        int* list = side ? list_tgt : list_src;

        if (tid < 32) lc[tid] = 0;
        __syncthreads();

        #pragma unroll 4
        for (int it = 0; it < 32; it++) {        // 32768 edges, int4 per thread
            const int e0 = it * 1024 + tid * 4;
            int4 v = *(const int4*)(E + e0);
            int c;
            c = v.x - base;
            if ((unsigned)c < 32u) { int s = atomicAdd(&lc[c], 1);
                if (s < CAP) list[(base + c) * CAP + s] = e0; }
            c = v.y - base;
            if ((unsigned)c < 32u) { int s = atomicAdd(&lc[c], 1);
                if (s < CAP) list[(base + c) * CAP + s] = e0 + 1; }
            c = v.z - base;
            if ((unsigned)c < 32u) { int s = atomicAdd(&lc[c], 1);
                if (s < CAP) list[(base + c) * CAP + s] = e0 + 2; }
            c = v.w - base;
            if ((unsigned)c < 32u) { int s = atomicAdd(&lc[c], 1);
                if (s < CAP) list[(base + c) * CAP + s] = e0 + 3; }
        }
        __syncthreads();
        if (tid < 32) cnt[side * 1024 + base + tid] = min(lc[tid], CAP);
    }
}

// ---------------------------------------------------------------------------
// K2 "gather": edge MLP inlined + atomic-free sparse contraction.
// One block per (side, column). The bucket's own H-row is block-constant
// (L1-hot), so each edge eval needs only ONE other-side H-row read — same
// total L2 traffic as the old standalone edge kernel, minus one dispatch.
//  MLP: 8x 16-lane groups, lane u owns h = u*8..u*8+7, shfl_xor reduce.
//  Contraction: LDS-staged coefs/indices -> ~32 independent 512 B row reads.
// ---------------------------------------------------------------------------
__global__ __launch_bounds__(128) void gather_kernel(
    const int* __restrict__ src, const int* __restrict__ tgt,
    const int* __restrict__ cnt,
    const int* __restrict__ list_src, const int* __restrict__ list_tgt,
    const float* __restrict__ HimgT, const float* __restrict__ HtxtT,
    const float* __restrict__ w2, const float* __restrict__ b2,
    const float* __restrict__ imgT, const float* __restrict__ textT,
    float* __restrict__ out)
{
    __shared__ float avl[CAP];
    __shared__ int   ol[CAP];
    const int blk = blockIdx.x, b = threadIdx.x;
    const int side = blk >> 10, c = blk & 1023;
    int n = cnt[side * 1024 + c];               // already clamped to CAP
    const int* lst = (side ? list_tgt : list_src) + c * CAP;
    const int* oth = side ? src : tgt;
    const float* Hown = (side ? HtxtT : HimgT) + c * 128;
    const float* Hoth = side ? HimgT : HtxtT;
    const float* T    = side ? imgT : textT;

    if (b < n)
        ol[b] = oth[lst[b]];
    __syncthreads();

    // ---- inline edge MLP: a = sigmoid(w2 . relu(Hown + Hoth[o]) + b2) ----
    {
        const int u = b & 15;                    // h-segment owner
        const int group = (b >> 6) * 4 + ((b & 63) >> 4);   // 0..7
        const float4 wa = *(const float4*)(w2 + u * 8);
        const float4 wb = *(const float4*)(w2 + u * 8 + 4);
        const float4 o0 = *(const float4*)(Hown + u * 8);
        const float4 o1 = *(const float4*)(Hown + u * 8 + 4);
        const float b2v = b2[0];
        for (int p = group; p < n; p += 8) {
            const float* Hr = Hoth + ol[p] * 128 + u * 8;
            float4 g0 = *(const float4*)(Hr);
            float4 g1 = *(const float4*)(Hr + 4);
            float x;
            x  = fmaxf(o0.x + g0.x, 0.f) * wa.x;
            x += fmaxf(o0.y + g0.y, 0.f) * wa.y;
            x += fmaxf(o0.z + g0.z, 0.f) * wa.z;
            x += fmaxf(o0.w + g0.w, 0.f) * wa.w;
            x += fmaxf(o1.x + g1.x, 0.f) * wb.x;
            x += fmaxf(o1.y + g1.y, 0.f) * wb.y;
            x += fmaxf(o1.z + g1.z, 0.f) * wb.z;
            x += fmaxf(o1.w + g1.w, 0.f) * wb.w;
            #pragma unroll
            for (int off = 1; off < 16; off <<= 1)
                x += __shfl_xor(x, off, 64);     // reduce within 16-lane group
            if (u == 0)
                avl[p] = 1.f / (1.f + expf(-(x + b2v)));
        }
    }
    __syncthreads();

    // ---- contraction: out[side][b][c] = sum_p avl[p] * T[ol[p]*128 + b] ----
    float acc0 = 0.f, acc1 = 0.f;
    int p = 0;
    for (; p + 1 < n; p += 2) {
        acc0 += avl[p]     * T[ol[p]     * 128 + b];  // LDS broadcast + 512B row
        acc1 += avl[p + 1] * T[ol[p + 1] * 128 + b];
    }
    if (p < n) acc0 += avl[p] * T[ol[p] * 128 + b];

    out[side * (BD * NCOL) + b * 1024 + c] = acc0 + acc1;
}

extern "C" void kernel_launch(void* const* d_in, const int* in_sizes, int n_in,
                              void* d_out, int out_size, void* d_ws, size_t ws_size,
                              hipStream_t stream)
{
    const float* img  = (const float*)d_in[0];   // [128,1024]
    const float* text = (const float*)d_in[1];   // [128,1024]
    const int*   src  = (const int*)  d_in[2];   // [32768]
    const int*   tgt  = (const int*)  d_in[3];   // [32768]
    const float* W1   = (const float*)d_in[4];   // [128,256]
    const float* b1   = (const float*)d_in[5];   // [128]
    const float* w2   = (const float*)d_in[6];   // [128]
    const float* b2   = (const float*)d_in[7];   // [1]
    float* out = (float*)d_out;                  // 2 x [128,1024] concat

    // workspace: ~3.2 MB, no memset needed anywhere
    float* HimgT  = (float*)d_ws;           // 131072 (b1 folded in)
    float* HtxtT  = HimgT + 131072;         // 131072
    float* imgT   = HtxtT + 131072;         // 131072  imgT[i*128+b]
    float* textT  = imgT  + 131072;         // 131072  textT[t*128+b]
    int* cnt      = (int*)(textT + 131072); // 2048 (written fully by prep)
    int* list_src = cnt + 2048;             // 1024*CAP
    int* list_tgt = list_src + 1024 * CAP;  // 1024*CAP

    prep_kernel<<<576, 256, 0, stream>>>(img, text, src, tgt, W1, b1,
                                         HimgT, HtxtT, imgT, textT,
                                         cnt, list_src, list_tgt);
    gather_kernel<<<2048, 128, 0, stream>>>(src, tgt, cnt,
                                            list_src, list_tgt,
                                            HimgT, HtxtT, w2, b2,
                                            imgT, textT, out);
}